// Round 8
// baseline (406.717 us; speedup 1.0000x reference)
//
#include <hip/hip_runtime.h>
#include <hip/hip_bf16.h>

// GQA block for MI355X. bf16 MFMA, fp32 accumulation.
// Pipeline:
//   prep: cvt X -> bf16 (Xb) + all weight transposes, ONE launch
//   gemm (m97 pattern, BK=64, XOR-swizzled LDS, global_load_lds staging):
//     Qb [4096,2048], Kb [4096,512], Vt [512,4096] (V transposed + token-permuted)
//   flash attention (32x32x16 MFMA): 512-thr blocks, 8 waves = 4 heads x 2 KEY-HALVES;
//     16 waves/CU (2 blocks x 8). Swapped QK^T, in-register softmax, double-buffered
//     K/V (1 barrier/tile), linear cross-wave merge at end (fixed-max softmax).
//   gemm: out = Ab @ Wo + bo (fp32)

typedef __attribute__((ext_vector_type(8))) short short8;
typedef __attribute__((ext_vector_type(4))) short short4v;
typedef __attribute__((ext_vector_type(4))) float float4v;
typedef __attribute__((ext_vector_type(16))) float float16v;

#define C1F 0.12751743f   // (1/sqrt(128)) * log2(e)
#define B0F -16.0f        // fixed max offset in log2 units

#if defined(__has_builtin) && __has_builtin(__builtin_amdgcn_exp2f)
#define EXP2(x) __builtin_amdgcn_exp2f(x)
#else
#define EXP2(x) exp2f(x)
#endif

__device__ __forceinline__ short f2bf(float x) {
    __hip_bfloat16 h = __float2bfloat16(x);
    short s; __builtin_memcpy(&s, &h, sizeof(s)); return s;
}

__device__ __forceinline__ void gl16(const short* g, short* l) {
    __builtin_amdgcn_global_load_lds(
        (const __attribute__((address_space(1))) void*)g,
        (__attribute__((address_space(3))) void*)l, 16, 0, 0);
}

// ---------------- prep: X->bf16 AND weight transposes in ONE launch ----------------
__global__ __launch_bounds__(256) void prep_kernel(
    const float* __restrict__ X, short* __restrict__ Xb,
    const float* __restrict__ Wq, const float* __restrict__ Wk,
    const float* __restrict__ Wv, const float* __restrict__ Wo,
    short* __restrict__ WqkvT, short* __restrict__ Wot) {
    __shared__ float tile[32][33];
    const int bxg = blockIdx.x;
    if (bxg < 8192) {
        int i = (bxg * 256 + threadIdx.x) * 4;
        float4 v = *(const float4*)(X + i);
        short4v o;
        o[0] = f2bf(v.x); o[1] = f2bf(v.y); o[2] = f2bf(v.z); o[3] = f2bf(v.w);
        *(short4v*)(Xb + i) = o;
        return;
    }
    const int tid = bxg - 8192;
    int bx = tid % 160;
    const int k0 = (tid / 160) * 32;
    const float* W; short* Wt; int N;
    if (bx < 64)      { W = Wq; Wt = WqkvT;                      N = 2048; }
    else if (bx < 80) { W = Wk; Wt = WqkvT + (size_t)2048 * 2048; N = 512; bx -= 64; }
    else if (bx < 96) { W = Wv; Wt = WqkvT + (size_t)2560 * 2048; N = 512; bx -= 80; }
    else              { W = Wo; Wt = Wot;                        N = 2048; bx -= 96; }
    const int K = 2048;
    const int n0 = bx * 32;
    const int tx = threadIdx.x & 31, ty = threadIdx.x >> 5;
#pragma unroll
    for (int i = 0; i < 4; ++i) {
        int kk = ty + i * 8;
        tile[kk][tx] = W[(size_t)(k0 + kk) * N + n0 + tx];
    }
    __syncthreads();
#pragma unroll
    for (int i = 0; i < 4; ++i) {
        int nn = ty + i * 8;
        Wt[(size_t)(n0 + nn) * K + k0 + tx] = f2bf(tile[tx][nn]);
    }
}

// ---------------- GEMM: C = A[M,K] @ Bt[N,K]^T + bias ----------------
// 128x128 tile, BK=64, 4 waves, single-buffered (m97 2-barrier structure).
// LDS XOR-swizzled (T2, both sides): stage LDS[row][slot] = G[row][slot ^ (row&7)],
// read phys slot = (ks*4+quad) ^ (l15&7).
// mode 0: fused QKV epilogue (Q->O0, K->O1, V->O2 transposed + token-permute bits2<->3)
// mode 1: fp32 out Of [*,2048] + b0
__global__ __launch_bounds__(256) void gemm_dma_kernel(
    const short* __restrict__ A, const short* __restrict__ Bt,
    const float* __restrict__ b0, const float* __restrict__ b1, const float* __restrict__ b2,
    short* __restrict__ O0, short* __restrict__ O1, short* __restrict__ O2,
    float* __restrict__ Of, int K, int mode) {
    __shared__ short As[128 * 64];
    __shared__ short Bs[128 * 64];
    const int t = threadIdx.x, lane = t & 63, w = t >> 6;
    const int l15 = lane & 15, quad = lane >> 4;
    const int wm = (w & 1) * 64, wn = (w >> 1) * 64;
    const int m0 = blockIdx.y * 128, n0 = blockIdx.x * 128;
    const int r8 = lane >> 3;                        // 0..7 (== row&7 of staged row)
    const int csw = ((lane & 7) ^ r8) * 8;           // pre-swizzled source col (shorts)
    const short* ga = A + (size_t)(m0 + w * 8 + r8) * K + csw;
    const short* gb = Bt + (size_t)(n0 + w * 8 + r8) * K + csw;
    short* lA = As + (w * 8) * 64;   // wave-uniform LDS base; dst = base + lane*16B
    short* lB = Bs + (w * 8) * 64;
    const int xs = l15 & 7;                          // read-side row&7

    float4v acc[4][4] = {};

    for (int k0 = 0; k0 < K; k0 += 64) {
#pragma unroll
        for (int c = 0; c < 4; ++c) {
            gl16(ga + k0 + (size_t)(c * 32) * K, lA + c * 2048);
            gl16(gb + k0 + (size_t)(c * 32) * K, lB + c * 2048);
        }
        __syncthreads();   // drains vmcnt -> staging visible
#pragma unroll
        for (int ks = 0; ks < 2; ++ks) {
            short8 af[4], bfr[4];
            const int ps = ((ks * 4 + quad) ^ xs) * 8;
#pragma unroll
            for (int i = 0; i < 4; ++i)
                af[i] = *(const short8*)(As + (wm + i * 16 + l15) * 64 + ps);
#pragma unroll
            for (int j = 0; j < 4; ++j)
                bfr[j] = *(const short8*)(Bs + (wn + j * 16 + l15) * 64 + ps);
#pragma unroll
            for (int i = 0; i < 4; ++i)
#pragma unroll
                for (int j = 0; j < 4; ++j)
                    acc[i][j] = __builtin_amdgcn_mfma_f32_16x16x32_bf16(af[i], bfr[j], acc[i][j], 0, 0, 0);
        }
        __syncthreads();   // all reads done before next staging overwrite
    }

#pragma unroll
    for (int i = 0; i < 4; ++i) {
#pragma unroll
        for (int j = 0; j < 4; ++j) {
            const int col = n0 + wn + j * 16 + l15;
            const int row0 = m0 + wm + i * 16 + quad * 4;
            if (mode == 1) {
                const float bc = b0[col];
#pragma unroll
                for (int r = 0; r < 4; ++r)
                    Of[(size_t)(row0 + r) * 2048 + col] = acc[i][j][r] + bc;
            } else if (col < 2048) {
                const float bc = b0[col];
#pragma unroll
                for (int r = 0; r < 4; ++r)
                    O0[(size_t)(row0 + r) * 2048 + col] = f2bf(acc[i][j][r] + bc);
            } else if (col < 2560) {
                const int c = col - 2048;
                const float bc = b1[c];
#pragma unroll
                for (int r = 0; r < 4; ++r)
                    O1[(size_t)(row0 + r) * 512 + c] = f2bf(acc[i][j][r] + bc);
            } else {
                const int c = col - 2560;
                const float bc = b2[c];
                // token permutation for flash PV slot order: bits 2<->3 of within-16 index
                const int qsw = ((quad & 1) << 1) | (quad >> 1);
                const int prow = m0 + wm + i * 16 + qsw * 4;
#pragma unroll
                for (int r = 0; r < 4; ++r)
                    O2[(size_t)c * 4096 + prow + r] = f2bf(acc[i][j][r] + bc);
            }
        }
    }
}

// ---------------- Flash attention, 8 waves, key-split, in-register softmax ----------
// grid (S/32, G, B), 512 threads = 8 waves. Wave w: head = g + 4*(w&3),
// key-half ks = w>>2 of each 64-key tile. 32 q-rows per block (all waves same rows).
// Swapped QK^T: st = mfma(Kfrag, Qfrag) -> st[reg] = S[key, q=lane&31], key =
// ks*32 + (reg&3)+8*(reg>>2)+4*(lane>>5). Softmax in-register (fixed-max exp2 ->
// cross-wave merge is LINEAR). PV uses V key-slots cc = ks*2+{0,1} (Vt token-permuted).
// K/V double-buffered: ONE barrier/tile; 2-tile register prefetch; mask fast-path;
// softmax/PV half-pipeline. End: pair (w, w+4) merges o/rsum via LDS (aliases K/V bufs).
__global__ __launch_bounds__(512, 4) void flash_kernel(
    const short* __restrict__ Qb, const short* __restrict__ Kb,
    const short* __restrict__ Vt, const int* __restrict__ mask,
    short* __restrict__ Ab) {
    __shared__ __align__(16) char smem[71680];
    short* KsBase = (short*)smem;                 // 2 x [64*136] shorts = 34,816 B
    short* VsBase = (short*)(smem + 34816);       // 2 x [128*72] shorts = 36,864 B
    float* mg = (float*)smem;                     // merge alias: 4*64*65*4 = 66,560 B

    const int t = threadIdx.x;
    const int lane = t & 63, w = t >> 6;            // w in 0..7
    const int l31 = lane & 31, hi = lane >> 5;
    const int ksp = w >> 2;                         // key-half of this wave
    const int qt = blockIdx.x, g = blockIdx.y, b = blockIdx.z;
    const int h = g + 4 * (w & 3);
    const int q0 = qt * 32;

    short8 qf[8];
#pragma unroll
    for (int dd = 0; dd < 8; ++dd)
        qf[dd] = *(const short8*)(Qb + (size_t)(b * 2048 + q0 + l31) * 2048
                                  + h * 128 + dd * 16 + hi * 8);

    float16v o[4] = {};
    float rsum = 0.f;

    // staging (512 threads): K rows kR,kR+32 ; V rows vR,vR+64
    const int kR = t >> 4, kC = (t & 15) * 8;       // kR in 0..31
    const int vR = t >> 3, vC = (t & 7) * 8;        // vR in 0..63
    const short* kg = Kb + (size_t)(b * 2048 + kR) * 512 + g * 128 + kC;
    const short* vg = Vt + (size_t)(g * 128 + vR) * 4096 + (size_t)b * 2048 + vC;

    short8 kv[2], vv[2];
    int mvr = 1;

#define LOADT(KB)                                                                  \
    do {                                                                           \
        kv[0] = *(const short8*)(kg + (size_t)(KB) * 512);                         \
        kv[1] = *(const short8*)(kg + (size_t)((KB) + 32) * 512);                  \
        vv[0] = *(const short8*)(vg + (KB));                                       \
        vv[1] = *(const short8*)(vg + (size_t)64 * 4096 + (KB));                   \
        mvr = mask[b * 2048 + (KB) + lane];                                        \
    } while (0)

#define STAGE(BUF)                                                                 \
    do {                                                                           \
        short* Ksw = KsBase + (BUF) * (64 * 136);                                  \
        short* Vsw = VsBase + (BUF) * (128 * 72);                                  \
        *(short8*)(Ksw + kR * 136 + kC) = kv[0];                                   \
        *(short8*)(Ksw + (kR + 32) * 136 + kC) = kv[1];                            \
        *(short8*)(Vsw + vR * 72 + vC) = vv[0];                                    \
        *(short8*)(Vsw + (vR + 64) * 72 + vC) = vv[1];                             \
    } while (0)

    LOADT(0);
    STAGE(0);
    unsigned long long bits = __ballot(mvr != 0);
    LOADT(64);
    __syncthreads();   // buf0 visible

    int cur = 0;
    unsigned long long bits_next = bits;

    for (int kt = 0; kt < 32; ++kt) {
        if (kt + 1 < 32) {
            STAGE(cur ^ 1);
            bits_next = __ballot(mvr != 0);
            if (kt + 2 < 32) LOADT((kt + 2) * 64);
        }
        const short* Ksb = KsBase + cur * (64 * 136);
        const short* Vsb = VsBase + cur * (128 * 72);

        // S^T (this wave's 32-key half): st[reg] = S[key = ksp*32 + koff + 4*hi, q=l31]
        float16v st = {};
        __builtin_amdgcn_s_setprio(1);
#pragma unroll
        for (int dd = 0; dd < 8; ++dd) {
            short8 kf = *(const short8*)(Ksb + (ksp * 32 + l31) * 136 + dd * 16 + hi * 8);
            st = __builtin_amdgcn_mfma_f32_32x32x16_bf16(kf, qf[dd], st, 0, 0, 0);
        }
        __builtin_amdgcn_s_setprio(0);

        const bool full = (bits == ~0ull);
        const unsigned int mword =
            (unsigned int)(ksp ? (bits >> 32) : bits) >> (4 * hi);

        // softmax lower 8 regs (key offsets 0..3, 8..11 within half)
        if (full) {
#pragma unroll
            for (int e = 0; e < 8; ++e) {
                float p = EXP2(fmaf(st[e], C1F, B0F));
                rsum += p; st[e] = p;
            }
        } else {
#pragma unroll
            for (int e = 0; e < 8; ++e) {
                const int koff = (e & 3) + 8 * (e >> 2);
                float p = EXP2(fmaf(st[e], C1F, B0F));
                p = ((mword >> koff) & 1) ? p : 0.f;
                rsum += p; st[e] = p;
            }
        }

        // PV first V-slot group (cc = ksp*2); softmax upper half overlaps on VALU
        {
            const int cc = ksp * 2;
            short8 pa;
#pragma unroll
            for (int e = 0; e < 8; ++e) pa[e] = f2bf(st[e]);
            __builtin_amdgcn_s_setprio(1);
#pragma unroll
            for (int db = 0; db < 4; ++db) {
                short8 vb = *(const short8*)(Vsb + (db * 32 + l31) * 72 + cc * 16 + hi * 8);
                o[db] = __builtin_amdgcn_mfma_f32_32x32x16_bf16(pa, vb, o[db], 0, 0, 0);
            }
            __builtin_amdgcn_s_setprio(0);
        }

        // softmax upper 8 regs (key offsets 16..19, 24..27 within half)
        if (full) {
#pragma unroll
            for (int e = 8; e < 16; ++e) {
                float p = EXP2(fmaf(st[e], C1F, B0F));
                rsum += p; st[e] = p;
            }
        } else {
#pragma unroll
            for (int e = 8; e < 16; ++e) {
                const int koff = (e & 3) + 8 * (e >> 2);
                float p = EXP2(fmaf(st[e], C1F, B0F));
                p = ((mword >> koff) & 1) ? p : 0.f;
                rsum += p; st[e] = p;
            }
        }

        // PV second V-slot group (cc = ksp*2 + 1)
        {
            const int cc = ksp * 2 + 1;
            short8 pa;
#pragma unroll
            for (int e = 0; e < 8; ++e) pa[e] = f2bf(st[8 + e]);
            __builtin_amdgcn_s_setprio(1);
#pragma unroll
            for (int db = 0; db < 4; ++db) {
                short8 vb = *(const short8*)(Vsb + (db * 32 + l31) * 72 + cc * 16 + hi * 8);
                o[db] = __builtin_amdgcn_mfma_f32_32x32x16_bf16(pa, vb, o[db], 0, 0, 0);
            }
            __builtin_amdgcn_s_setprio(0);
        }

        __syncthreads();   // all waves done reading buf[cur]; kt+1 staging complete
        bits = bits_next;
        cur ^= 1;
    }
#undef LOADT
#undef STAGE

    // combine hi-halves within wave (lanes l and l+32 hold same q, different keys)
    rsum += __shfl_xor(rsum, 32, 64);

    // cross-wave pair merge (w, w+4): high waves publish, low waves consume.
    // (loop ended with __syncthreads -> K/V bufs dead, safe to alias)
    if (w >= 4) {
        const int base = (w - 4) * (64 * 65) + lane * 65;
#pragma unroll
        for (int db = 0; db < 4; ++db)
#pragma unroll
            for (int e = 0; e < 16; ++e)
                mg[base + db * 16 + e] = o[db][e];
        mg[base + 64] = rsum;
    }
    __syncthreads();
    if (w < 4) {
        const int base = w * (64 * 65) + lane * 65;
#pragma unroll
        for (int db = 0; db < 4; ++db)
#pragma unroll
            for (int e = 0; e < 16; ++e)
                o[db][e] += mg[base + db * 16 + e];
        rsum += mg[base + 64];

        const float rinv = (rsum > 0.f) ? 1.f / rsum : 0.f;
        float rq[16];
#pragma unroll
        for (int e = 0; e < 16; ++e) {
            const int koff = (e & 3) + 8 * (e >> 2);
            rq[e] = __shfl(rinv, koff + 4 * hi, 64);
        }
        const size_t ob = (size_t)(b * 2048 + q0) * 2048 + h * 128;
#pragma unroll
        for (int db = 0; db < 4; ++db)
#pragma unroll
            for (int e = 0; e < 16; ++e) {
                const int koff = (e & 3) + 8 * (e >> 2);
                Ab[ob + (size_t)(koff + 4 * hi) * 2048 + db * 32 + l31] =
                    f2bf(o[db][e] * rq[e]);
            }
    }
}

extern "C" void kernel_launch(void* const* d_in, const int* in_sizes, int n_in,
                              void* d_out, int out_size, void* d_ws, size_t ws_size,
                              hipStream_t stream) {
    (void)in_sizes; (void)n_in; (void)out_size; (void)ws_size;
    const float* X  = (const float*)d_in[0];
    const int* mask = (const int*)d_in[1];
    const float* Wq = (const float*)d_in[2];
    const float* bq = (const float*)d_in[3];
    const float* Wk = (const float*)d_in[4];
    const float* bk = (const float*)d_in[5];
    const float* Wv = (const float*)d_in[6];
    const float* bv = (const float*)d_in[7];
    const float* Wo = (const float*)d_in[8];
    const float* bo = (const float*)d_in[9];
    float* out = (float*)d_out;

    char* ws = (char*)d_ws;
    short* Xb     = (short*)(ws + 0);          // 16,777,216 B (reused as Ab)
    short* WqkvT  = (short*)(ws + 16777216);   // 12,582,912 B [3072,2048]
    short* Wot    = (short*)(ws + 29360128);   //  8,388,608 B
    short* Qb     = (short*)(ws + 37748736);   // 16,777,216 B
    short* Kb     = (short*)(ws + 54525952);   //  4,194,304 B
    short* Vt     = (short*)(ws + 58720256);   //  4,194,304 B
    short* Ab     = Xb;

    const int HID = 2048;

    // cvt (8192 blocks) + all transposes (10240 blocks) in one launch
    prep_kernel<<<18432, 256, 0, stream>>>(X, Xb, Wq, Wk, Wv, Wo, WqkvT, Wot);

    // fused Q|K|V projection: N = 3072
    gemm_dma_kernel<<<dim3(24, 32), 256, 0, stream>>>(
        Xb, WqkvT, bq, bk, bv, Qb, Kb, Vt, nullptr, HID, 0);

    flash_kernel<<<dim3(64, 4, 2), 512, 0, stream>>>(Qb, Kb, Vt, mask, Ab);

    gemm_dma_kernel<<<dim3(16, 32), 256, 0, stream>>>(
        Ab, Wot, bo, nullptr, nullptr, nullptr, nullptr, nullptr, out, HID, 1);
}

// Round 9
// 304.697 us; speedup vs baseline: 1.3348x; 1.3348x over previous
//
#include <hip/hip_runtime.h>
#include <hip/hip_bf16.h>

// GQA block for MI355X. bf16 MFMA, fp32 accumulation.
// Pipeline:
//   prep: cvt X -> bf16 (Xb) + all weight transposes, ONE launch
//   gemm (m97 pattern, BK=64, XOR-swizzled LDS, global_load_lds staging, XCD-chunked
//     block swizzle): Qb [4096,2048], Kb [4096,512], Vt [512,4096] (V transposed +
//     token-permuted bits2<->3 for flash PV slot order)
//   flash attention (32x32x16 MFMA): 256-thr blocks (4 waves = 4 heads of one group),
//     swapped QK^T, in-register softmax, double-buffered K/V (1 barrier/tile),
//     mask fast-path, softmax/PV half-pipeline.   [R7 known-good: 85.7 us]
//   gemm: out = Ab @ Wo + bo (fp32)

typedef __attribute__((ext_vector_type(8))) short short8;
typedef __attribute__((ext_vector_type(4))) short short4v;
typedef __attribute__((ext_vector_type(4))) float float4v;
typedef __attribute__((ext_vector_type(16))) float float16v;

#define C1F 0.12751743f   // (1/sqrt(128)) * log2(e)
#define B0F -16.0f        // fixed max offset in log2 units

#if defined(__has_builtin) && __has_builtin(__builtin_amdgcn_exp2f)
#define EXP2(x) __builtin_amdgcn_exp2f(x)
#else
#define EXP2(x) exp2f(x)
#endif

__device__ __forceinline__ short f2bf(float x) {
    __hip_bfloat16 h = __float2bfloat16(x);
    short s; __builtin_memcpy(&s, &h, sizeof(s)); return s;
}

__device__ __forceinline__ void gl16(const short* g, short* l) {
    __builtin_amdgcn_global_load_lds(
        (const __attribute__((address_space(1))) void*)g,
        (__attribute__((address_space(3))) void*)l, 16, 0, 0);
}

// ---------------- prep: X->bf16 AND weight transposes in ONE launch ----------------
__global__ __launch_bounds__(256) void prep_kernel(
    const float* __restrict__ X, short* __restrict__ Xb,
    const float* __restrict__ Wq, const float* __restrict__ Wk,
    const float* __restrict__ Wv, const float* __restrict__ Wo,
    short* __restrict__ WqkvT, short* __restrict__ Wot) {
    __shared__ float tile[32][33];
    const int bxg = blockIdx.x;
    if (bxg < 8192) {
        int i = (bxg * 256 + threadIdx.x) * 4;
        float4 v = *(const float4*)(X + i);
        short4v o;
        o[0] = f2bf(v.x); o[1] = f2bf(v.y); o[2] = f2bf(v.z); o[3] = f2bf(v.w);
        *(short4v*)(Xb + i) = o;
        return;
    }
    const int tid = bxg - 8192;
    int bx = tid % 160;
    const int k0 = (tid / 160) * 32;
    const float* W; short* Wt; int N;
    if (bx < 64)      { W = Wq; Wt = WqkvT;                      N = 2048; }
    else if (bx < 80) { W = Wk; Wt = WqkvT + (size_t)2048 * 2048; N = 512; bx -= 64; }
    else if (bx < 96) { W = Wv; Wt = WqkvT + (size_t)2560 * 2048; N = 512; bx -= 80; }
    else              { W = Wo; Wt = Wot;                        N = 2048; bx -= 96; }
    const int K = 2048;
    const int n0 = bx * 32;
    const int tx = threadIdx.x & 31, ty = threadIdx.x >> 5;
#pragma unroll
    for (int i = 0; i < 4; ++i) {
        int kk = ty + i * 8;
        tile[kk][tx] = W[(size_t)(k0 + kk) * N + n0 + tx];
    }
    __syncthreads();
#pragma unroll
    for (int i = 0; i < 4; ++i) {
        int nn = ty + i * 8;
        Wt[(size_t)(n0 + nn) * K + k0 + tx] = f2bf(tile[tx][nn]);
    }
}

// ---------------- GEMM: C = A[M,K] @ Bt[N,K]^T + bias ----------------
// 128x128 tile, BK=64, 4 waves, single-buffered (m97 2-barrier structure).
// LDS XOR-swizzled (T2, both sides): stage LDS[row][slot] = G[row][slot ^ (row&7)],
// read phys slot = (ks*4+quad) ^ (l15&7).
// XCD-chunked block swizzle (T1): bijective since grid count % 8 == 0 -> each XCD
// gets consecutive tile-rows (A-panel reuse in its private L2).
// mode 0: fused QKV epilogue (Q->O0, K->O1, V->O2 transposed + token-permute bits2<->3)
// mode 1: fp32 out Of [*,2048] + b0
__global__ __launch_bounds__(256) void gemm_dma_kernel(
    const short* __restrict__ A, const short* __restrict__ Bt,
    const float* __restrict__ b0, const float* __restrict__ b1, const float* __restrict__ b2,
    short* __restrict__ O0, short* __restrict__ O1, short* __restrict__ O2,
    float* __restrict__ Of, int K, int mode) {
    __shared__ short As[128 * 64];
    __shared__ short Bs[128 * 64];
    const int t = threadIdx.x, lane = t & 63, w = t >> 6;
    const int l15 = lane & 15, quad = lane >> 4;
    const int wm = (w & 1) * 64, wn = (w >> 1) * 64;

    // T1: XCD-chunked bijective remap (requires gridDim.x*gridDim.y % 8 == 0)
    const int nwg = gridDim.x * gridDim.y;
    int bid = blockIdx.y * gridDim.x + blockIdx.x;
    bid = (bid & 7) * (nwg >> 3) + (bid >> 3);
    const int m0 = (bid / gridDim.x) * 128, n0 = (bid % gridDim.x) * 128;

    const int r8 = lane >> 3;                        // 0..7 (== row&7 of staged row)
    const int csw = ((lane & 7) ^ r8) * 8;           // pre-swizzled source col (shorts)
    const short* ga = A + (size_t)(m0 + w * 8 + r8) * K + csw;
    const short* gb = Bt + (size_t)(n0 + w * 8 + r8) * K + csw;
    short* lA = As + (w * 8) * 64;   // wave-uniform LDS base; dst = base + lane*16B
    short* lB = Bs + (w * 8) * 64;
    const int xs = l15 & 7;                          // read-side row&7

    float4v acc[4][4] = {};

    for (int k0 = 0; k0 < K; k0 += 64) {
#pragma unroll
        for (int c = 0; c < 4; ++c) {
            gl16(ga + k0 + (size_t)(c * 32) * K, lA + c * 2048);
            gl16(gb + k0 + (size_t)(c * 32) * K, lB + c * 2048);
        }
        __syncthreads();   // drains vmcnt -> staging visible
#pragma unroll
        for (int ks = 0; ks < 2; ++ks) {
            short8 af[4], bfr[4];
            const int ps = ((ks * 4 + quad) ^ xs) * 8;
#pragma unroll
            for (int i = 0; i < 4; ++i)
                af[i] = *(const short8*)(As + (wm + i * 16 + l15) * 64 + ps);
#pragma unroll
            for (int j = 0; j < 4; ++j)
                bfr[j] = *(const short8*)(Bs + (wn + j * 16 + l15) * 64 + ps);
#pragma unroll
            for (int i = 0; i < 4; ++i)
#pragma unroll
                for (int j = 0; j < 4; ++j)
                    acc[i][j] = __builtin_amdgcn_mfma_f32_16x16x32_bf16(af[i], bfr[j], acc[i][j], 0, 0, 0);
        }
        __syncthreads();   // all reads done before next staging overwrite
    }

#pragma unroll
    for (int i = 0; i < 4; ++i) {
#pragma unroll
        for (int j = 0; j < 4; ++j) {
            const int col = n0 + wn + j * 16 + l15;
            const int row0 = m0 + wm + i * 16 + quad * 4;
            if (mode == 1) {
                const float bc = b0[col];
#pragma unroll
                for (int r = 0; r < 4; ++r)
                    Of[(size_t)(row0 + r) * 2048 + col] = acc[i][j][r] + bc;
            } else if (col < 2048) {
                const float bc = b0[col];
#pragma unroll
                for (int r = 0; r < 4; ++r)
                    O0[(size_t)(row0 + r) * 2048 + col] = f2bf(acc[i][j][r] + bc);
            } else if (col < 2560) {
                const int c = col - 2048;
                const float bc = b1[c];
#pragma unroll
                for (int r = 0; r < 4; ++r)
                    O1[(size_t)(row0 + r) * 512 + c] = f2bf(acc[i][j][r] + bc);
            } else {
                const int c = col - 2560;
                const float bc = b2[c];
                // token permutation for flash PV slot order: bits 2<->3 of within-16 index
                const int qsw = ((quad & 1) << 1) | (quad >> 1);
                const int prow = m0 + wm + i * 16 + qsw * 4;
                short4v ov;
#pragma unroll
                for (int r = 0; r < 4; ++r) ov[r] = f2bf(acc[i][j][r] + bc);
                *(short4v*)(O2 + (size_t)c * 4096 + prow) = ov;   // 4 consecutive rows
            }
        }
    }
}

// ---------------- Flash attention, 32x32 MFMA, in-register softmax (R7) ------------
// grid (S/32, G, B), 256 threads = 4 waves. Wave w: head = g + 4*w.
// Swapped QK^T: st = mfma(Kfrag, Qfrag) -> st[reg] = S[key, q=lane&31] with
// key = (reg&3)+8*(reg>>2)+4*(lane>>5) (+32 for st1). Softmax in-register.
// PV A-frag: straight bf16 pack of st regs (Vt token-permuted at gemm epilogue).
// K/V double-buffered in LDS: ONE barrier per tile; loads prefetched 2 tiles deep.
// Mask fast-path; softmax(st1) overlapped under PV(st0) MFMAs.
__global__ __launch_bounds__(256, 2) void flash_kernel(
    const short* __restrict__ Qb, const short* __restrict__ Kb,
    const short* __restrict__ Vt, const int* __restrict__ mask,
    short* __restrict__ Ab) {
    __shared__ short Ks[2][64 * 136];   // keys x d, stride pad 136
    __shared__ short Vs[2][128 * 72];   // d x key-slot, stride pad 72

    const int t = threadIdx.x;
    const int lane = t & 63, w = t >> 6;            // w in 0..3
    const int l31 = lane & 31, hi = lane >> 5;
    const int qt = blockIdx.x, g = blockIdx.y, b = blockIdx.z;
    const int h = g + 4 * w;
    const int q0 = qt * 32;

    short8 qf[8];
#pragma unroll
    for (int dd = 0; dd < 8; ++dd)
        qf[dd] = *(const short8*)(Qb + (size_t)(b * 2048 + q0 + l31) * 2048
                                  + h * 128 + dd * 16 + hi * 8);

    float16v o[4] = {};
    float rsum = 0.f;

    const int kR = t >> 4, kC = (t & 15) * 8;  // K stage: rows kR+{0,16,32,48}
    const int vR = t >> 3, vC = (t & 7) * 8;   // V stage: rows vR+{0,32,64,96}
    const short* kg = Kb + (size_t)(b * 2048 + kR) * 512 + g * 128 + kC;
    const short* vg = Vt + (size_t)(g * 128 + vR) * 4096 + (size_t)b * 2048 + vC;

    short8 kv[4], vv[4];
    int mvr = 1;

#define LOADT(KB)                                                                  \
    do {                                                                           \
        kv[0] = *(const short8*)(kg + (size_t)(KB) * 512);                         \
        kv[1] = *(const short8*)(kg + (size_t)((KB) + 16) * 512);                  \
        kv[2] = *(const short8*)(kg + (size_t)((KB) + 32) * 512);                  \
        kv[3] = *(const short8*)(kg + (size_t)((KB) + 48) * 512);                  \
        vv[0] = *(const short8*)(vg + (KB));                                       \
        vv[1] = *(const short8*)(vg + (size_t)32 * 4096 + (KB));                   \
        vv[2] = *(const short8*)(vg + (size_t)64 * 4096 + (KB));                   \
        vv[3] = *(const short8*)(vg + (size_t)96 * 4096 + (KB));                   \
        mvr = mask[b * 2048 + (KB) + lane];                                        \
    } while (0)

#define STAGE(BUF)                                                                 \
    do {                                                                           \
        _Pragma("unroll")                                                          \
        for (int i_ = 0; i_ < 4; ++i_)                                             \
            *(short8*)(&Ks[BUF][(kR + i_ * 16) * 136 + kC]) = kv[i_];              \
        _Pragma("unroll")                                                          \
        for (int i_ = 0; i_ < 4; ++i_)                                             \
            *(short8*)(&Vs[BUF][(vR + i_ * 32) * 72 + vC]) = vv[i_];               \
    } while (0)

    LOADT(0);
    STAGE(0);
    unsigned long long bits = __ballot(mvr != 0);
    LOADT(64);
    __syncthreads();   // buf0 visible

    int cur = 0;
    unsigned long long bits_next = bits;

    for (int kt = 0; kt < 32; ++kt) {
        if (kt + 1 < 32) {
            STAGE(cur ^ 1);
            bits_next = __ballot(mvr != 0);
            if (kt + 2 < 32) LOADT((kt + 2) * 64);
        }
        const short* Ksb = &Ks[cur][0];
        const short* Vsb = &Vs[cur][0];

        float16v st0 = {}, st1 = {};
        __builtin_amdgcn_s_setprio(1);
#pragma unroll
        for (int dd = 0; dd < 8; ++dd) {
            short8 kf0 = *(const short8*)(Ksb + l31 * 136 + dd * 16 + hi * 8);
            short8 kf1 = *(const short8*)(Ksb + (32 + l31) * 136 + dd * 16 + hi * 8);
            st0 = __builtin_amdgcn_mfma_f32_32x32x16_bf16(kf0, qf[dd], st0, 0, 0, 0);
            st1 = __builtin_amdgcn_mfma_f32_32x32x16_bf16(kf1, qf[dd], st1, 0, 0, 0);
        }
        __builtin_amdgcn_s_setprio(0);

        const bool full = (bits == ~0ull);
        const unsigned int mlo = ((unsigned int)bits) >> (4 * hi);
        const unsigned int mhi = ((unsigned int)(bits >> 32)) >> (4 * hi);

        if (full) {
#pragma unroll
            for (int e = 0; e < 16; ++e) {
                float p0 = EXP2(fmaf(st0[e], C1F, B0F));
                rsum += p0; st0[e] = p0;
            }
        } else {
#pragma unroll
            for (int e = 0; e < 16; ++e) {
                const int koff = (e & 3) + 8 * (e >> 2);
                float p0 = EXP2(fmaf(st0[e], C1F, B0F));
                p0 = ((mlo >> koff) & 1) ? p0 : 0.f;
                rsum += p0; st0[e] = p0;
            }
        }

        __builtin_amdgcn_s_setprio(1);
#pragma unroll
        for (int cc = 0; cc < 2; ++cc) {
            short8 pa;
#pragma unroll
            for (int e = 0; e < 8; ++e) pa[e] = f2bf(st0[cc * 8 + e]);
#pragma unroll
            for (int db = 0; db < 4; ++db) {
                short8 vb = *(const short8*)(Vsb + (db * 32 + l31) * 72 + cc * 16 + hi * 8);
                o[db] = __builtin_amdgcn_mfma_f32_32x32x16_bf16(pa, vb, o[db], 0, 0, 0);
            }
        }
        __builtin_amdgcn_s_setprio(0);

        if (full) {
#pragma unroll
            for (int e = 0; e < 16; ++e) {
                float p1 = EXP2(fmaf(st1[e], C1F, B0F));
                rsum += p1; st1[e] = p1;
            }
        } else {
#pragma unroll
            for (int e = 0; e < 16; ++e) {
                const int koff = (e & 3) + 8 * (e >> 2);
                float p1 = EXP2(fmaf(st1[e], C1F, B0F));
                p1 = ((mhi >> koff) & 1) ? p1 : 0.f;
                rsum += p1; st1[e] = p1;
            }
        }

        __builtin_amdgcn_s_setprio(1);
#pragma unroll
        for (int cc = 2; cc < 4; ++cc) {
            short8 pa;
#pragma unroll
            for (int e = 0; e < 8; ++e) pa[e] = f2bf(st1[(cc & 1) * 8 + e]);
#pragma unroll
            for (int db = 0; db < 4; ++db) {
                short8 vb = *(const short8*)(Vsb + (db * 32 + l31) * 72 + cc * 16 + hi * 8);
                o[db] = __builtin_amdgcn_mfma_f32_32x32x16_bf16(pa, vb, o[db], 0, 0, 0);
            }
        }
        __builtin_amdgcn_s_setprio(0);

        __syncthreads();
        bits = bits_next;
        cur ^= 1;
    }
#undef LOADT
#undef STAGE

    rsum += __shfl_xor(rsum, 32, 64);
    const float rinv = (rsum > 0.f) ? 1.f / rsum : 0.f;
    float rq[16];
#pragma unroll
    for (int e = 0; e < 16; ++e) {
        const int koff = (e & 3) + 8 * (e >> 2);
        rq[e] = __shfl(rinv, koff + 4 * hi, 64);
    }
    const size_t ob = (size_t)(b * 2048 + q0) * 2048 + h * 128;
#pragma unroll
    for (int db = 0; db < 4; ++db)
#pragma unroll
        for (int e = 0; e < 16; ++e) {
            const int koff = (e & 3) + 8 * (e >> 2);
            Ab[ob + (size_t)(koff + 4 * hi) * 2048 + db * 32 + l31] =
                f2bf(o[db][e] * rq[e]);
        }
}

extern "C" void kernel_launch(void* const* d_in, const int* in_sizes, int n_in,
                              void* d_out, int out_size, void* d_ws, size_t ws_size,
                              hipStream_t stream) {
    (void)in_sizes; (void)n_in; (void)out_size; (void)ws_size;
    const float* X  = (const float*)d_in[0];
    const int* mask = (const int*)d_in[1];
    const float* Wq = (const float*)d_in[2];
    const float* bq = (const float*)d_in[3];
    const float* Wk = (const float*)d_in[4];
    const float* bk = (const float*)d_in[5];
    const float* Wv = (const float*)d_in[6];
    const float* bv = (const float*)d_in[7];
    const float* Wo = (const float*)d_in[8];
    const float* bo = (const float*)d_in[9];
    float* out = (float*)d_out;

    char* ws = (char*)d_ws;
    short* Xb     = (short*)(ws + 0);          // 16,777,216 B (reused as Ab)
    short* WqkvT  = (short*)(ws + 16777216);   // 12,582,912 B [3072,2048]
    short* Wot    = (short*)(ws + 29360128);   //  8,388,608 B
    short* Qb     = (short*)(ws + 37748736);   // 16,777,216 B
    short* Kb     = (short*)(ws + 54525952);   //  4,194,304 B
    short* Vt     = (short*)(ws + 58720256);   //  4,194,304 B
    short* Ab     = Xb;

    const int HID = 2048;

    // cvt (8192 blocks) + all transposes (10240 blocks) in one launch
    prep_kernel<<<18432, 256, 0, stream>>>(X, Xb, Wq, Wk, Wv, Wo, WqkvT, Wot);

    // fused Q|K|V projection: N = 3072 (768 blocks, %8==0 for T1)
    gemm_dma_kernel<<<dim3(24, 32), 256, 0, stream>>>(
        Xb, WqkvT, bq, bk, bv, Qb, Kb, Vt, nullptr, HID, 0);

    flash_kernel<<<dim3(64, 4, 2), 256, 0, stream>>>(Qb, Kb, Vt, mask, Ab);

    // out = Ab @ Wo + bo (512 blocks, %8==0 for T1)
    gemm_dma_kernel<<<dim3(16, 32), 256, 0, stream>>>(
        Ab, Wot, bo, nullptr, nullptr, nullptr, nullptr, nullptr, out, HID, 1);
}